// Round 6
// baseline (749.123 us; speedup 1.0000x reference)
//
#include <hip/hip_runtime.h>

#define LARGE_F 1e30f
#define LOG2E_F 1.4426950408889634f
#define LN2_F   0.6931471805599453f

constexpr int BB = 128;
constexpr int NN = 512;
constexpr int MM = 512;
constexpr int KK = 64;
constexpr int NDIAG = NN + MM - 1;   // 1023
constexpr int PCELLS = 263680;       // padded (4-float-aligned) cells per batch

// ---- 4-float-aligned antidiagonal slot layout -------------------------------
__device__ __forceinline__ int slot_off(int p) {
    if (p < NN) { const int a = p >> 2, r = p & 3; return ((a + 1) * (2 * a + r)) << 2; }
    const int t = p - NN, a = t >> 2, r = t & 3;
    return 132096 + (t << 9) - ((a * (2 * a + r - 1)) << 2);
}
__device__ __forceinline__ int imin4(int p) {
    return (p < NN) ? 0 : ((p - (NN - 1)) & ~3);
}
__device__ __forceinline__ int read_base(int p) { return slot_off(p) - imin4(p); }

// lane i <- lane i-1 via DPP wave_shr:1 (VALU, no LDS round-trip).
__device__ __forceinline__ float wave_shr1(float v, float bound) {
    const int r = __builtin_amdgcn_update_dpp(__float_as_int(bound), __float_as_int(v),
                                              0x138, 0xf, 0xf, false);
    return __int_as_float(r);
}

// Async global->LDS DMA, 16B per lane: lane l's 16B land at ldst + 16*l.
#define GLOAD_LDS16(gsrc, ldst)                                                      \
    __builtin_amdgcn_global_load_lds(                                                \
        (const __attribute__((address_space(1))) void*)(gsrc),                       \
        (__attribute__((address_space(3))) void*)(ldst), 16, 0, 0)

// ---------------- Phase 1: D[b,i,j] = ||x_i - y_j||^2 into aligned diag slots.
__global__ __launch_bounds__(256, 4) void sdtw_dist(const float* __restrict__ x,
                                                    const float* __restrict__ y,
                                                    float* __restrict__ Dws) {
    __shared__ float xs[64][68];
    __shared__ float ys[64][68];
    __shared__ float x2s[64];
    __shared__ float y2s[64];
    float (*dt)[66] = (float (*)[66])(&xs[0][0]);   // alias after k-loop

    const int b  = blockIdx.y;
    const int ti = (blockIdx.x >> 3) << 6;
    const int tj = (blockIdx.x & 7) << 6;
    const int t  = threadIdx.x;

    const float* xb = x + ((size_t)b * NN + ti) * KK;
    const float* yb = y + ((size_t)b * MM + tj) * KK;

    {
        const int r0 = t >> 4;
        const int c0 = (t & 15) << 2;
#pragma unroll
        for (int q = 0; q < 4; ++q) {
            const int r = r0 + (q << 4);
            const float4 xv = *(const float4*)(xb + r * KK + c0);
            const float4 yv = *(const float4*)(yb + r * KK + c0);
            *(float4*)(&xs[r][c0]) = xv;
            *(float4*)(&ys[r][c0]) = yv;
        }
    }
    __syncthreads();

    if (t < 128) {
        const int r = t & 63;
        const float* row = (t < 64) ? &xs[r][0] : &ys[r][0];
        float s = 0.f;
#pragma unroll
        for (int k = 0; k < KK; k += 4) {
            const float4 v = *(const float4*)(row + k);
            s = fmaf(v.x, v.x, s); s = fmaf(v.y, v.y, s);
            s = fmaf(v.z, v.z, s); s = fmaf(v.w, v.w, s);
        }
        if (t < 64) x2s[r] = s; else y2s[r] = s;
    }
    __syncthreads();

    const int ty = t >> 4;
    const int tx = t & 15;

    float acc[4][4] = {};
    for (int k0 = 0; k0 < KK; k0 += 4) {
        float4 xa[4], yv[4];
#pragma unroll
        for (int a = 0; a < 4; ++a) xa[a] = *(const float4*)(&xs[(a << 4) + ty][k0]);
#pragma unroll
        for (int c = 0; c < 4; ++c) yv[c] = *(const float4*)(&ys[(c << 4) + tx][k0]);
#pragma unroll
        for (int a = 0; a < 4; ++a) {
#pragma unroll
            for (int c = 0; c < 4; ++c) {
                acc[a][c] = fmaf(xa[a].x, yv[c].x, acc[a][c]);
                acc[a][c] = fmaf(xa[a].y, yv[c].y, acc[a][c]);
                acc[a][c] = fmaf(xa[a].z, yv[c].z, acc[a][c]);
                acc[a][c] = fmaf(xa[a].w, yv[c].w, acc[a][c]);
            }
        }
    }
    __syncthreads();

#pragma unroll
    for (int a = 0; a < 4; ++a) {
        const float xx = x2s[(a << 4) + ty];
#pragma unroll
        for (int c = 0; c < 4; ++c) {
            dt[(a << 4) + ty][(c << 4) + tx] = xx + y2s[(c << 4) + tx] - 2.f * acc[a][c];
        }
    }
    __syncthreads();

    {
        const int w    = t >> 6;
        const int lane = t & 63;
        float* Db = Dws + (size_t)b * PCELLS;
        for (int q = w; q < 127; q += 4) {
            const int i_lo = (q > 63) ? (q - 63) : 0;
            const int i_hi = (q < 63) ? q : 63;
            const int len  = i_hi - i_lo + 1;
            if (lane < len) {
                const int il = i_lo + lane;
                const int p  = ti + tj + q;
                Db[slot_off(p) + (ti + il) - imin4(p)] = dt[il][q - il];
            }
        }
    }
}

// ---------------- Phase 2: one wave per batch, 8 rows/lane, all-register DP.
// 16-diagonal LDS ring filled by global_load_lds DMA (no dest VGPR -> no
// untracked register hazard); counted s_waitcnt vmcnt(30) + sched_barrier(0)
// before each slot's ds_read. Prefetch distance 16 steps (~3700 cyc) hides
// HBM latency; consumption is compiler-tracked ds_read_b128 (auto lgkmcnt).
__global__ __launch_bounds__(64, 1) void sdtw_dp(const float* __restrict__ Dws,
                                                 float* __restrict__ out) {
    __shared__ float ring[16][512];      // 32 KB
    const int b    = blockIdx.x;
    const int lane = threadIdx.x;
    const float* __restrict__ Db  = Dws + (size_t)b * PCELLS;
    const float* __restrict__ Dbl = Db + 4 * lane;   // per-lane 16B source

    float A[8], Bv[8];
#pragma unroll
    for (int c = 0; c < 8; ++c) { A[c] = LARGE_F; Bv[c] = LARGE_F; }

    // Branch-free DMA of one diagonal (2 x 1KB). Clamped slots never consumed;
    // clamped addresses stay inside the batch's PCELLS region.
    auto issue = [&](int pd, int slot) {
        const int pc = (pd < NDIAG - 1) ? pd : (NDIAG - 1);
        const float* src = Dbl + read_base(pc);
        GLOAD_LDS16(src,       &ring[slot][0]);
        GLOAD_LDS16(src + 256, &ring[slot][256]);
    };

    auto dp_step = [&](bool first, float (&P)[8], float (&P2)[8], int slot) {
        const float4 u0 = *(const float4*)(&ring[slot][8 * lane]);
        const float4 u1 = *(const float4*)(&ring[slot][8 * lane + 4]);
        const float D[8] = {u0.x, u0.y, u0.z, u0.w, u1.x, u1.y, u1.z, u1.w};
        float shp  = wave_shr1(P[7],  LARGE_F);
        float shp2 = wave_shr1(P2[7], LARGE_F);
        if (first && lane == 0) shp2 = 0.f;
#pragma unroll
        for (int c = 7; c >= 0; --c) {       // descending: in-place P2 overwrite
            const float w  = P[c];
            const float n  = (c == 0) ? shp  : P[c - 1];
            const float nw = (c == 0) ? shp2 : P2[c - 1];
            const float mn = fminf(fminf(w, n), nw);
            const float mx = fmaxf(fmaxf(w, n), nw);
            const float md = __builtin_amdgcn_fmed3f(w, n, nw);
            const float sm = mn - log2f(1.0f + exp2f(mn - md) + exp2f(mn - mx));
            P2[c] = fmaf(D[c], LOG2E_F, sm);
        }
    };

#define RING_WAIT()                                          \
    asm volatile("s_waitcnt vmcnt(30)" ::: "memory");        \
    __builtin_amdgcn_sched_barrier(0)

    // Prologue: 32 DMAs in flight (diags 0..15).
#pragma unroll
    for (int s = 0; s < 16; ++s) issue(s, s);

#pragma unroll 1
    for (int pb = 0; pb < 1024; pb += 16) {
#pragma unroll
        for (int s = 0; s < 16; s += 2) {
            RING_WAIT();
            dp_step(pb == 0 && s == 0, A, Bv, s);   // even p: result -> Bv
            issue(pb + 16 + s, s);
            RING_WAIT();
            dp_step(false, Bv, A, s + 1);           // odd p: result -> A
            issue(pb + 16 + s + 1, s + 1);
        }
    }
    // Step 1022 (even) wrote R'_1022 into Bv; cell (511,511) = lane 63, c=7.
    if (lane == 63) out[b] = Bv[7] * LN2_F;
#undef RING_WAIT
}

// ---------------- Fallback (only if ws too small): fused, correct, slow.
__global__ __launch_bounds__(512) void sdtw_fused_naive(const float* __restrict__ x,
                                                        const float* __restrict__ y,
                                                        float* __restrict__ out) {
    __shared__ float rbuf[3][NN];
    __shared__ float y2s[MM];
    const int b = blockIdx.x;
    const int i = threadIdx.x;

    const float* xrow  = x + ((size_t)b * NN + i) * KK;
    const float* ybase = y + (size_t)b * MM * KK;

    float xr[KK];
    float x2 = 0.f;
#pragma unroll
    for (int k = 0; k < KK; k += 4) {
        const float4 v = *(const float4*)(xrow + k);
        xr[k] = v.x; xr[k + 1] = v.y; xr[k + 2] = v.z; xr[k + 3] = v.w;
        x2 = fmaf(v.x, v.x, fmaf(v.y, v.y, fmaf(v.z, v.z, fmaf(v.w, v.w, x2))));
    }
    {
        const float* yrow = ybase + (size_t)i * KK;
        float s = 0.f;
#pragma unroll
        for (int k = 0; k < KK; k += 4) {
            const float4 v = *(const float4*)(yrow + k);
            s = fmaf(v.x, v.x, s); s = fmaf(v.y, v.y, s);
            s = fmaf(v.z, v.z, s); s = fmaf(v.w, v.w, s);
        }
        y2s[i] = s;
    }
    rbuf[0][i] = LARGE_F;
    rbuf[1][i] = LARGE_F;
    rbuf[2][i] = LARGE_F;

    float* row_w  = rbuf[0];
    float* row_p  = rbuf[2];
    float* row_p2 = rbuf[1];
    __syncthreads();

    float cur = LARGE_F;
    for (int p = 0; p < NDIAG; ++p) {
        const int j0 = p - i;
        const bool valid = (j0 >= 0) && (j0 < MM);
        float dg = 0.f;
        if (valid) {
            const float* yrow = ybase + (size_t)j0 * KK;
            float dot = 0.f;
#pragma unroll
            for (int k = 0; k < KK; k += 4) {
                const float4 v = *(const float4*)(yrow + k);
                dot = fmaf(xr[k], v.x, dot);
                dot = fmaf(xr[k + 1], v.y, dot);
                dot = fmaf(xr[k + 2], v.z, dot);
                dot = fmaf(xr[k + 3], v.w, dot);
            }
            dg = x2 + y2s[j0] - 2.f * dot;
        }
        const float r_w  = row_p[i];
        const float r_n  = (i > 0) ? row_p[i - 1] : LARGE_F;
        const float r_nw = (i > 0) ? row_p2[i - 1] : ((p == 0) ? 0.f : LARGE_F);

        const float m = fminf(fminf(r_nw, r_n), r_w);
        const float s = __expf(m - r_nw) + __expf(m - r_n) + __expf(m - r_w);
        const float softmin = m - __logf(s);

        cur = valid ? (dg + softmin) : LARGE_F;
        row_w[i] = cur;
        __syncthreads();

        float* tmp = row_w;
        row_w = row_p2; row_p2 = row_p; row_p = tmp;
    }
    if (i == NN - 1) out[b] = cur;
}

extern "C" void kernel_launch(void* const* d_in, const int* in_sizes, int n_in,
                              void* d_out, int out_size, void* d_ws, size_t ws_size,
                              hipStream_t stream) {
    const float* x = (const float*)d_in[0];
    const float* y = (const float*)d_in[1];
    float* out = (float*)d_out;

    const size_t need = (size_t)BB * PCELLS * sizeof(float);  // 135,004,160 B
    if (ws_size >= need) {
        float* Dws = (float*)d_ws;
        sdtw_dist<<<dim3(64, BB), 256, 0, stream>>>(x, y, Dws);
        sdtw_dp<<<dim3(BB), 64, 0, stream>>>(Dws, out);
    } else {
        sdtw_fused_naive<<<dim3(BB), 512, 0, stream>>>(x, y, out);
    }
}

// Round 7
// 632.557 us; speedup vs baseline: 1.1843x; 1.1843x over previous
//
#include <hip/hip_runtime.h>

#define LARGE_F 1e30f
#define LOG2E_F 1.4426950408889634f
#define LN2_F   0.6931471805599453f

constexpr int BB = 128;
constexpr int NN = 512;
constexpr int MM = 512;
constexpr int KK = 64;
constexpr int NDIAG = NN + MM - 1;   // 1023
constexpr int PCELLS = 263680;       // padded (4-float-aligned) cells per batch

// ---- 4-float-aligned antidiagonal slot layout -------------------------------
__device__ __forceinline__ int slot_off(int p) {
    if (p < NN) { const int a = p >> 2, r = p & 3; return ((a + 1) * (2 * a + r)) << 2; }
    const int t = p - NN, a = t >> 2, r = t & 3;
    return 132096 + (t << 9) - ((a * (2 * a + r - 1)) << 2);
}
__device__ __forceinline__ int imin4(int p) {
    return (p < NN) ? 0 : ((p - (NN - 1)) & ~3);
}
__device__ __forceinline__ int read_base(int p) { return slot_off(p) - imin4(p); }

// lane i <- lane i-1 via DPP wave_shr:1 (VALU, no LDS round-trip).
__device__ __forceinline__ float wave_shr1(float v, float bound) {
    const int r = __builtin_amdgcn_update_dpp(__float_as_int(bound), __float_as_int(v),
                                              0x138, 0xf, 0xf, false);
    return __int_as_float(r);
}

// Async global->LDS DMA, 16B per lane: lane l's 16B land at ldst + 16*l.
#define GLOAD_LDS16(gsrc, ldst)                                                      \
    __builtin_amdgcn_global_load_lds(                                                \
        (const __attribute__((address_space(1))) void*)(gsrc),                       \
        (__attribute__((address_space(3))) void*)(ldst), 16, 0, 0)

// ---------------- Phase 1: D[b,i,j] = ||x_i - y_j||^2 into aligned diag slots.
__global__ __launch_bounds__(256, 4) void sdtw_dist(const float* __restrict__ x,
                                                    const float* __restrict__ y,
                                                    float* __restrict__ Dws) {
    __shared__ float xs[64][68];
    __shared__ float ys[64][68];
    __shared__ float x2s[64];
    __shared__ float y2s[64];
    float (*dt)[66] = (float (*)[66])(&xs[0][0]);   // alias after k-loop

    const int b  = blockIdx.y;
    const int ti = (blockIdx.x >> 3) << 6;
    const int tj = (blockIdx.x & 7) << 6;
    const int t  = threadIdx.x;

    const float* xb = x + ((size_t)b * NN + ti) * KK;
    const float* yb = y + ((size_t)b * MM + tj) * KK;

    {
        const int r0 = t >> 4;
        const int c0 = (t & 15) << 2;
#pragma unroll
        for (int q = 0; q < 4; ++q) {
            const int r = r0 + (q << 4);
            const float4 xv = *(const float4*)(xb + r * KK + c0);
            const float4 yv = *(const float4*)(yb + r * KK + c0);
            *(float4*)(&xs[r][c0]) = xv;
            *(float4*)(&ys[r][c0]) = yv;
        }
    }
    __syncthreads();

    if (t < 128) {
        const int r = t & 63;
        const float* row = (t < 64) ? &xs[r][0] : &ys[r][0];
        float s = 0.f;
#pragma unroll
        for (int k = 0; k < KK; k += 4) {
            const float4 v = *(const float4*)(row + k);
            s = fmaf(v.x, v.x, s); s = fmaf(v.y, v.y, s);
            s = fmaf(v.z, v.z, s); s = fmaf(v.w, v.w, s);
        }
        if (t < 64) x2s[r] = s; else y2s[r] = s;
    }
    __syncthreads();

    const int ty = t >> 4;
    const int tx = t & 15;

    float acc[4][4] = {};
    for (int k0 = 0; k0 < KK; k0 += 4) {
        float4 xa[4], yv[4];
#pragma unroll
        for (int a = 0; a < 4; ++a) xa[a] = *(const float4*)(&xs[(a << 4) + ty][k0]);
#pragma unroll
        for (int c = 0; c < 4; ++c) yv[c] = *(const float4*)(&ys[(c << 4) + tx][k0]);
#pragma unroll
        for (int a = 0; a < 4; ++a) {
#pragma unroll
            for (int c = 0; c < 4; ++c) {
                acc[a][c] = fmaf(xa[a].x, yv[c].x, acc[a][c]);
                acc[a][c] = fmaf(xa[a].y, yv[c].y, acc[a][c]);
                acc[a][c] = fmaf(xa[a].z, yv[c].z, acc[a][c]);
                acc[a][c] = fmaf(xa[a].w, yv[c].w, acc[a][c]);
            }
        }
    }
    __syncthreads();

#pragma unroll
    for (int a = 0; a < 4; ++a) {
        const float xx = x2s[(a << 4) + ty];
#pragma unroll
        for (int c = 0; c < 4; ++c) {
            dt[(a << 4) + ty][(c << 4) + tx] = xx + y2s[(c << 4) + tx] - 2.f * acc[a][c];
        }
    }
    __syncthreads();

    {
        const int w    = t >> 6;
        const int lane = t & 63;
        float* Db = Dws + (size_t)b * PCELLS;
        for (int q = w; q < 127; q += 4) {
            const int i_lo = (q > 63) ? (q - 63) : 0;
            const int i_hi = (q < 63) ? q : 63;
            const int len  = i_hi - i_lo + 1;
            if (lane < len) {
                const int il = i_lo + lane;
                const int p  = ti + tj + q;
                Db[slot_off(p) + (ti + il) - imin4(p)] = dt[il][q - il];
            }
        }
    }
}

// ---------------- Phase 2: one wave per batch, 8 rows/lane, all-register DP.
// Double-buffered 16-diagonal LDS blocks filled by global_load_lds DMA.
// One counted s_waitcnt vmcnt(32) per 16-step block: the newest 32 DMAs are
// the NEXT block's, so <=32 outstanding implies the current block's buffer is
// complete. Worst case (compiler adds a conservative drain at the block's
// first ds_read) costs one HBM latency per 16 steps -- amortized ~70 cyc/step.
__global__ __launch_bounds__(64, 1) void sdtw_dp(const float* __restrict__ Dws,
                                                 float* __restrict__ out) {
    __shared__ float ring[2][16][512];   // 64 KB
    const int b    = blockIdx.x;
    const int lane = threadIdx.x;
    const float* __restrict__ Db  = Dws + (size_t)b * PCELLS;
    const float* __restrict__ Dbl = Db + 4 * lane;   // per-lane 16B source

    float A[8], Bv[8];
#pragma unroll
    for (int c = 0; c < 8; ++c) { A[c] = LARGE_F; Bv[c] = LARGE_F; }

    // Issue 16 diagonals (32 DMAs) into buffer `buf`. Clamped diags are never
    // consumed; clamped addresses stay inside the batch's PCELLS region.
    auto issue16 = [&](int pd0, int buf) {
#pragma unroll
        for (int s = 0; s < 16; ++s) {
            const int pd = pd0 + s;
            const int pc = (pd < NDIAG - 1) ? pd : (NDIAG - 1);
            const float* src = Dbl + read_base(pc);
            GLOAD_LDS16(src,       &ring[buf][s][0]);
            GLOAD_LDS16(src + 256, &ring[buf][s][256]);
        }
    };

    auto dp_step = [&](bool first, float (&P)[8], float (&P2)[8], int buf, int slot) {
        const float4 u0 = *(const float4*)(&ring[buf][slot][8 * lane]);
        const float4 u1 = *(const float4*)(&ring[buf][slot][8 * lane + 4]);
        const float D[8] = {u0.x, u0.y, u0.z, u0.w, u1.x, u1.y, u1.z, u1.w};
        float shp  = wave_shr1(P[7],  LARGE_F);
        float shp2 = wave_shr1(P2[7], LARGE_F);
        if (first && lane == 0) shp2 = 0.f;
#pragma unroll
        for (int c = 7; c >= 0; --c) {       // descending: in-place P2 overwrite
            const float w  = P[c];
            const float n  = (c == 0) ? shp  : P[c - 1];
            const float nw = (c == 0) ? shp2 : P2[c - 1];
            const float mn = fminf(fminf(w, n), nw);
            const float mx = fmaxf(fmaxf(w, n), nw);
            const float md = __builtin_amdgcn_fmed3f(w, n, nw);
            const float sm = mn - log2f(1.0f + exp2f(mn - md) + exp2f(mn - mx));
            P2[c] = fmaf(D[c], LOG2E_F, sm);
        }
    };

    // Prologue: block 0 (diags 0..15) into buf 0.
    issue16(0, 0);

#pragma unroll 1
    for (int k = 0; k < 64; ++k) {
        issue16((k + 1) << 4, (k + 1) & 1);            // prefetch next block
        asm volatile("s_waitcnt vmcnt(32)" ::: "memory");  // current block done
        __builtin_amdgcn_sched_barrier(0);
        const int buf = k & 1;
#pragma unroll
        for (int s = 0; s < 16; s += 2) {
            dp_step(k == 0 && s == 0, A, Bv, buf, s);  // even p: result -> Bv
            dp_step(false, Bv, A, buf, s + 1);         // odd p: result -> A
        }
    }
    // Step 1022 (even) wrote R'_1022 into Bv; cell (511,511) = lane 63, c=7.
    // Step 1023 (clamped garbage) only touched A -- Bv is intact.
    if (lane == 63) out[b] = Bv[7] * LN2_F;
}

// ---------------- Fallback (only if ws too small): fused, correct, slow.
__global__ __launch_bounds__(512) void sdtw_fused_naive(const float* __restrict__ x,
                                                        const float* __restrict__ y,
                                                        float* __restrict__ out) {
    __shared__ float rbuf[3][NN];
    __shared__ float y2s[MM];
    const int b = blockIdx.x;
    const int i = threadIdx.x;

    const float* xrow  = x + ((size_t)b * NN + i) * KK;
    const float* ybase = y + (size_t)b * MM * KK;

    float xr[KK];
    float x2 = 0.f;
#pragma unroll
    for (int k = 0; k < KK; k += 4) {
        const float4 v = *(const float4*)(xrow + k);
        xr[k] = v.x; xr[k + 1] = v.y; xr[k + 2] = v.z; xr[k + 3] = v.w;
        x2 = fmaf(v.x, v.x, fmaf(v.y, v.y, fmaf(v.z, v.z, fmaf(v.w, v.w, x2))));
    }
    {
        const float* yrow = ybase + (size_t)i * KK;
        float s = 0.f;
#pragma unroll
        for (int k = 0; k < KK; k += 4) {
            const float4 v = *(const float4*)(yrow + k);
            s = fmaf(v.x, v.x, s); s = fmaf(v.y, v.y, s);
            s = fmaf(v.z, v.z, s); s = fmaf(v.w, v.w, s);
        }
        y2s[i] = s;
    }
    rbuf[0][i] = LARGE_F;
    rbuf[1][i] = LARGE_F;
    rbuf[2][i] = LARGE_F;

    float* row_w  = rbuf[0];
    float* row_p  = rbuf[2];
    float* row_p2 = rbuf[1];
    __syncthreads();

    float cur = LARGE_F;
    for (int p = 0; p < NDIAG; ++p) {
        const int j0 = p - i;
        const bool valid = (j0 >= 0) && (j0 < MM);
        float dg = 0.f;
        if (valid) {
            const float* yrow = ybase + (size_t)j0 * KK;
            float dot = 0.f;
#pragma unroll
            for (int k = 0; k < KK; k += 4) {
                const float4 v = *(const float4*)(yrow + k);
                dot = fmaf(xr[k], v.x, dot);
                dot = fmaf(xr[k + 1], v.y, dot);
                dot = fmaf(xr[k + 2], v.z, dot);
                dot = fmaf(xr[k + 3], v.w, dot);
            }
            dg = x2 + y2s[j0] - 2.f * dot;
        }
        const float r_w  = row_p[i];
        const float r_n  = (i > 0) ? row_p[i - 1] : LARGE_F;
        const float r_nw = (i > 0) ? row_p2[i - 1] : ((p == 0) ? 0.f : LARGE_F);

        const float m = fminf(fminf(r_nw, r_n), r_w);
        const float s = __expf(m - r_nw) + __expf(m - r_n) + __expf(m - r_w);
        const float softmin = m - __logf(s);

        cur = valid ? (dg + softmin) : LARGE_F;
        row_w[i] = cur;
        __syncthreads();

        float* tmp = row_w;
        row_w = row_p2; row_p2 = row_p; row_p = tmp;
    }
    if (i == NN - 1) out[b] = cur;
}

extern "C" void kernel_launch(void* const* d_in, const int* in_sizes, int n_in,
                              void* d_out, int out_size, void* d_ws, size_t ws_size,
                              hipStream_t stream) {
    const float* x = (const float*)d_in[0];
    const float* y = (const float*)d_in[1];
    float* out = (float*)d_out;

    const size_t need = (size_t)BB * PCELLS * sizeof(float);  // 135,004,160 B
    if (ws_size >= need) {
        float* Dws = (float*)d_ws;
        sdtw_dist<<<dim3(64, BB), 256, 0, stream>>>(x, y, Dws);
        sdtw_dp<<<dim3(BB), 64, 0, stream>>>(Dws, out);
    } else {
        sdtw_fused_naive<<<dim3(BB), 512, 0, stream>>>(x, y, out);
    }
}

// Round 8
// 356.846 us; speedup vs baseline: 2.0993x; 1.7726x over previous
//
#include <hip/hip_runtime.h>

#define LARGE_F 1e30f
#define LOG2E_F 1.4426950408889634f
#define LN2_F   0.6931471805599453f

constexpr int BB = 128;
constexpr int NN = 512;
constexpr int MM = 512;
constexpr int KK = 64;
constexpr int NDIAG = NN + MM - 1;   // 1023
constexpr int PCELLS = 263680;       // padded (4-float-aligned) cells per batch

// ---- 4-float-aligned antidiagonal slot layout -------------------------------
__device__ __forceinline__ int slot_off(int p) {
    if (p < NN) { const int a = p >> 2, r = p & 3; return ((a + 1) * (2 * a + r)) << 2; }
    const int t = p - NN, a = t >> 2, r = t & 3;
    return 132096 + (t << 9) - ((a * (2 * a + r - 1)) << 2);
}
__device__ __forceinline__ int imin4(int p) {
    return (p < NN) ? 0 : ((p - (NN - 1)) & ~3);
}
__device__ __forceinline__ int read_base(int p) { return slot_off(p) - imin4(p); }

// lane i <- lane i-1 via DPP wave_shr:1 (VALU, no LDS round-trip). Lane 0
// receives `bound` (old operand, bound_ctrl=false). HW-verified rounds 2-7.
__device__ __forceinline__ float wave_shr1(float v, float bound) {
    const int r = __builtin_amdgcn_update_dpp(__float_as_int(bound), __float_as_int(v),
                                              0x138, 0xf, 0xf, false);
    return __int_as_float(r);
}

// ---------------- Phase 1: D[b,i,j] = ||x_i - y_j||^2 into aligned diag slots.
__global__ __launch_bounds__(256, 4) void sdtw_dist(const float* __restrict__ x,
                                                    const float* __restrict__ y,
                                                    float* __restrict__ Dws) {
    __shared__ float xs[64][68];
    __shared__ float ys[64][68];
    __shared__ float x2s[64];
    __shared__ float y2s[64];
    float (*dt)[66] = (float (*)[66])(&xs[0][0]);   // alias after k-loop

    const int b  = blockIdx.y;
    const int ti = (blockIdx.x >> 3) << 6;
    const int tj = (blockIdx.x & 7) << 6;
    const int t  = threadIdx.x;

    const float* xb = x + ((size_t)b * NN + ti) * KK;
    const float* yb = y + ((size_t)b * MM + tj) * KK;

    {
        const int r0 = t >> 4;
        const int c0 = (t & 15) << 2;
#pragma unroll
        for (int q = 0; q < 4; ++q) {
            const int r = r0 + (q << 4);
            const float4 xv = *(const float4*)(xb + r * KK + c0);
            const float4 yv = *(const float4*)(yb + r * KK + c0);
            *(float4*)(&xs[r][c0]) = xv;
            *(float4*)(&ys[r][c0]) = yv;
        }
    }
    __syncthreads();

    if (t < 128) {
        const int r = t & 63;
        const float* row = (t < 64) ? &xs[r][0] : &ys[r][0];
        float s = 0.f;
#pragma unroll
        for (int k = 0; k < KK; k += 4) {
            const float4 v = *(const float4*)(row + k);
            s = fmaf(v.x, v.x, s); s = fmaf(v.y, v.y, s);
            s = fmaf(v.z, v.z, s); s = fmaf(v.w, v.w, s);
        }
        if (t < 64) x2s[r] = s; else y2s[r] = s;
    }
    __syncthreads();

    const int ty = t >> 4;
    const int tx = t & 15;

    float acc[4][4] = {};
    for (int k0 = 0; k0 < KK; k0 += 4) {
        float4 xa[4], yv[4];
#pragma unroll
        for (int a = 0; a < 4; ++a) xa[a] = *(const float4*)(&xs[(a << 4) + ty][k0]);
#pragma unroll
        for (int c = 0; c < 4; ++c) yv[c] = *(const float4*)(&ys[(c << 4) + tx][k0]);
#pragma unroll
        for (int a = 0; a < 4; ++a) {
#pragma unroll
            for (int c = 0; c < 4; ++c) {
                acc[a][c] = fmaf(xa[a].x, yv[c].x, acc[a][c]);
                acc[a][c] = fmaf(xa[a].y, yv[c].y, acc[a][c]);
                acc[a][c] = fmaf(xa[a].z, yv[c].z, acc[a][c]);
                acc[a][c] = fmaf(xa[a].w, yv[c].w, acc[a][c]);
            }
        }
    }
    __syncthreads();

#pragma unroll
    for (int a = 0; a < 4; ++a) {
        const float xx = x2s[(a << 4) + ty];
#pragma unroll
        for (int c = 0; c < 4; ++c) {
            dt[(a << 4) + ty][(c << 4) + tx] = xx + y2s[(c << 4) + tx] - 2.f * acc[a][c];
        }
    }
    __syncthreads();

    {
        const int w    = t >> 6;
        const int lane = t & 63;
        float* Db = Dws + (size_t)b * PCELLS;
        for (int q = w; q < 127; q += 4) {
            const int i_lo = (q > 63) ? (q - 63) : 0;
            const int i_hi = (q < 63) ? q : 63;
            const int len  = i_hi - i_lo + 1;
            if (lane < len) {
                const int il = i_lo + lane;
                const int p  = ti + tj + q;
                Db[slot_off(p) + (ti + il) - imin4(p)] = dt[il][q - il];
            }
        }
    }
}

// ---------------- Phase 2: 512 threads (8 waves), thread i owns row i.
// Row state in registers; neighbor via DPP; 8 boundary floats via LDS.
// RAW s_barrier + manual lgkmcnt(0) only -> no vmcnt drain at barriers, so the
// depth-16 register prefetch of D (barrier-pinned, compiler-tracked) hides
// HBM/L3 latency. Invalid cells need no masking: j<0 self-propagates ~1e30;
// j>=512 cells become finite but are never read by any valid cell.
__global__ __launch_bounds__(512, 1) void sdtw_dp(const float* __restrict__ Dws,
                                                  float* __restrict__ out) {
    __shared__ float hnd[2][8];          // parity-double-buffered wave handoff
    const int b    = blockIdx.x;
    const int i    = threadIdx.x;        // row index
    const int lane = i & 63;
    const int wv   = i >> 6;
    const float* __restrict__ Db = Dws + (size_t)b * PCELLS;

    // State: r_w = R_{p-1}[i], r_n = R_{p-1}[i-1], r_nw = R_{p-2}[i-1].
    float r_w = LARGE_F, r_n = LARGE_F;
    float r_nw = (i == 0) ? 0.f : LARGE_F;   // (i==0 && p==0) -> 0
    float res = 0.f;

    // Depth-16 register prefetch of D diagonals (coalesced 4B/lane).
    float dreg[16];
#pragma unroll
    for (int s = 0; s < 16; ++s) dreg[s] = Db[read_base(s) + i];

#pragma unroll 1
    for (int pb = 0; pb < 1024; pb += 16) {
#pragma unroll
        for (int s = 0; s < 16; ++s) {
            const int ps = pb + s;
            const float mn = fminf(fminf(r_w, r_n), r_nw);
            const float mx = fmaxf(fmaxf(r_w, r_n), r_nw);
            const float md = __builtin_amdgcn_fmed3f(r_w, r_n, r_nw);
            const float sm = mn - log2f(1.0f + exp2f(mn - md) + exp2f(mn - mx));
            const float cur = fmaf(dreg[s], LOG2E_F, sm);
            if (ps == 1022) res = cur;

            // lane63 -> next wave's lane0 handoff (parity slot: no race with
            // next step's write, which targets the other slot).
            if (lane == 63) hnd[ps & 1][wv] = cur;
            asm volatile("s_waitcnt lgkmcnt(0)" ::: "memory");
            __builtin_amdgcn_s_barrier();        // raw: NO vmcnt drain
            asm volatile("" ::: "memory");

            float nbr = wave_shr1(cur, LARGE_F);
            const float h = hnd[ps & 1][(wv > 0) ? (wv - 1) : 0];
            if (lane == 0 && wv > 0) nbr = h;
            r_nw = r_n; r_n = nbr; r_w = cur;

            // Prefetch D for step ps+16 (clamped; tail re-reads are benign and
            // in-bounds: read_base(p)+511 < PCELLS for all p).
            const int pc = (ps + 16 < NDIAG) ? (ps + 16) : (NDIAG - 1);
            dreg[s] = Db[read_base(pc) + i];
        }
    }
    if (i == NN - 1) out[b] = res * LN2_F;   // cell (511,511) from step 1022
}

// ---------------- Fallback (only if ws too small): fused, correct, slow.
__global__ __launch_bounds__(512) void sdtw_fused_naive(const float* __restrict__ x,
                                                        const float* __restrict__ y,
                                                        float* __restrict__ out) {
    __shared__ float rbuf[3][NN];
    __shared__ float y2s[MM];
    const int b = blockIdx.x;
    const int i = threadIdx.x;

    const float* xrow  = x + ((size_t)b * NN + i) * KK;
    const float* ybase = y + (size_t)b * MM * KK;

    float xr[KK];
    float x2 = 0.f;
#pragma unroll
    for (int k = 0; k < KK; k += 4) {
        const float4 v = *(const float4*)(xrow + k);
        xr[k] = v.x; xr[k + 1] = v.y; xr[k + 2] = v.z; xr[k + 3] = v.w;
        x2 = fmaf(v.x, v.x, fmaf(v.y, v.y, fmaf(v.z, v.z, fmaf(v.w, v.w, x2))));
    }
    {
        const float* yrow = ybase + (size_t)i * KK;
        float s = 0.f;
#pragma unroll
        for (int k = 0; k < KK; k += 4) {
            const float4 v = *(const float4*)(yrow + k);
            s = fmaf(v.x, v.x, s); s = fmaf(v.y, v.y, s);
            s = fmaf(v.z, v.z, s); s = fmaf(v.w, v.w, s);
        }
        y2s[i] = s;
    }
    rbuf[0][i] = LARGE_F;
    rbuf[1][i] = LARGE_F;
    rbuf[2][i] = LARGE_F;

    float* row_w  = rbuf[0];
    float* row_p  = rbuf[2];
    float* row_p2 = rbuf[1];
    __syncthreads();

    float cur = LARGE_F;
    for (int p = 0; p < NDIAG; ++p) {
        const int j0 = p - i;
        const bool valid = (j0 >= 0) && (j0 < MM);
        float dg = 0.f;
        if (valid) {
            const float* yrow = ybase + (size_t)j0 * KK;
            float dot = 0.f;
#pragma unroll
            for (int k = 0; k < KK; k += 4) {
                const float4 v = *(const float4*)(yrow + k);
                dot = fmaf(xr[k], v.x, dot);
                dot = fmaf(xr[k + 1], v.y, dot);
                dot = fmaf(xr[k + 2], v.z, dot);
                dot = fmaf(xr[k + 3], v.w, dot);
            }
            dg = x2 + y2s[j0] - 2.f * dot;
        }
        const float r_w  = row_p[i];
        const float r_n  = (i > 0) ? row_p[i - 1] : LARGE_F;
        const float r_nw = (i > 0) ? row_p2[i - 1] : ((p == 0) ? 0.f : LARGE_F);

        const float m = fminf(fminf(r_nw, r_n), r_w);
        const float s = __expf(m - r_nw) + __expf(m - r_n) + __expf(m - r_w);
        const float softmin = m - __logf(s);

        cur = valid ? (dg + softmin) : LARGE_F;
        row_w[i] = cur;
        __syncthreads();

        float* tmp = row_w;
        row_w = row_p2; row_p2 = row_p; row_p = tmp;
    }
    if (i == NN - 1) out[b] = cur;
}

extern "C" void kernel_launch(void* const* d_in, const int* in_sizes, int n_in,
                              void* d_out, int out_size, void* d_ws, size_t ws_size,
                              hipStream_t stream) {
    const float* x = (const float*)d_in[0];
    const float* y = (const float*)d_in[1];
    float* out = (float*)d_out;

    const size_t need = (size_t)BB * PCELLS * sizeof(float);  // 135,004,160 B
    if (ws_size >= need) {
        float* Dws = (float*)d_ws;
        sdtw_dist<<<dim3(64, BB), 256, 0, stream>>>(x, y, Dws);
        sdtw_dp<<<dim3(BB), 512, 0, stream>>>(Dws, out);
    } else {
        sdtw_fused_naive<<<dim3(BB), 512, 0, stream>>>(x, y, out);
    }
}